// Round 14
// baseline (465.746 us; speedup 1.0000x reference)
//
#include <hip/hip_runtime.h>

#define NRAYS 2048
#define NSAMP 128
#define HID   256

typedef __attribute__((ext_vector_type(8))) _Float16 half8;
typedef __attribute__((ext_vector_type(4))) float f32x4;

__device__ __forceinline__ unsigned pack2(_Float16 a, _Float16 b){
  unsigned short ua = __builtin_bit_cast(unsigned short, a);
  unsigned short ub = __builtin_bit_cast(unsigned short, b);
  return (unsigned)ua | ((unsigned)ub << 16);
}

// e5m2 byte: fp16 with bottom 8 mantissa bits dropped (same exponent field).
// encode = RNE round fp16 -> top byte; decode = byte<<8 reinterpreted as fp16.
__device__ __forceinline__ unsigned char enc8(_Float16 x){
  unsigned short h = __builtin_bit_cast(unsigned short, x);
  unsigned short r = (unsigned short)(h + 0x7F + ((h >> 8) & 1));
  return (unsigned char)(r >> 8);
}
__device__ __forceinline__ half8 dec8(unsigned long long v){
  half8 r;
  #pragma unroll
  for (int j = 0; j < 8; ++j){
    unsigned short u = (unsigned short)(((v >> (8 * j)) & 0xFFull) << 8);
    r[j] = __builtin_bit_cast(_Float16, u);
  }
  return r;
}

// ---- weight preprocess: fp32 row-major [K][N] -> fp16 hi/lo packed [K/8][N][8], scaled x256
// half offsets in ws: W1hi 0, W1lo 65536, W2hi 131072, W2lo 196608,
//                     W3hi 262144 (padded N=16, 4096), W3lo 266240
__global__ void prep_kernel(const float* __restrict__ W1,
                            const float* __restrict__ W2,
                            const float* __restrict__ W3,
                            _Float16* __restrict__ out)
{
  int idx = blockIdx.x * 256 + threadIdx.x;
  float v; int pk, base, lstep;
  if (idx < 65536){
    int k = idx >> 8, n = idx & 255;
    v = W1[idx] * 256.f; pk = (((k >> 3) << 8) + n) * 8 + (k & 7); base = 0; lstep = 65536;
  } else if (idx < 131072){
    int j = idx - 65536; int k = j >> 8, n = j & 255;
    v = W2[j] * 256.f; pk = (((k >> 3) << 8) + n) * 8 + (k & 7); base = 131072; lstep = 65536;
  } else if (idx < 135168){
    int j = idx - 131072;
    int n = (j >> 3) & 15;
    int k = ((j >> 7) << 3) | (j & 7);
    v = (n < 4) ? W3[k * 4 + n] * 256.f : 0.f; pk = j; base = 262144; lstep = 4096;
  } else return;
  _Float16 hi = (_Float16)v;
  _Float16 lo = (_Float16)(v - (float)hi);
  out[base + pk] = hi;
  out[base + lstep + pk] = lo;
}

// Two 64-sample chunks per ray. Activation tile: fp16 hi (32KB) + e5m2 lo (16KB)
// -> block LDS ~53.3KB -> 3 blocks/CU (12 waves). Weights stay fp16 hi/lo.
// kk is a RUNTIME loop (r11 structure; no B hoisting -> no spills).
__launch_bounds__(256, 3)
__global__ void nerf_kernel(const float* __restrict__ pos,
                            const float* __restrict__ tvals,
                            const float* __restrict__ W0,
                            const float* __restrict__ b0,
                            const float* __restrict__ b1,
                            const float* __restrict__ b2,
                            const float* __restrict__ b3,
                            const _Float16* __restrict__ wsu,
                            float* __restrict__ out)
{
  __shared__ __align__(16) _Float16      hbuf_hi[64 * HID]; // 32 KB swizzled
  __shared__ __align__(16) unsigned char hbuf_l8[64 * HID]; // 16 KB swizzled e5m2
  __shared__ float xls[NSAMP * 3];
  __shared__ float tl[NSAMP];
  __shared__ __align__(16) float obuf[NSAMP * 4];
  __shared__ float stot;
  __shared__ float redf[2][5];
  __shared__ int   redi[2];

  const int t    = threadIdx.x;
  const int ray  = blockIdx.x;
  const int lane = t & 63;
  const int wv   = t >> 6;     // wave id 0..3
  const int ln   = lane & 15;
  const int hi   = lane >> 4;
  const int swzx = (ln & 7) << 4;   // fp16-plane swizzle (16B granules)
  const int swz8 = (ln & 7) << 3;   // lo8-plane swizzle (8B granules)
  const float USC = 1.f / 65536.f;

  // ---- stage inputs
  {
    const float* pbase = pos + (size_t)ray * NSAMP * 3;
    xls[t] = pbase[t];
    if (t < NSAMP) xls[256 + t] = pbase[256 + t];
    if (t < NSAMP) tl[t] = tvals[(size_t)ray * NSAMP + t];
  }
  __syncthreads();

  const int c = (t & 127) << 1;   // two adjacent cols per thread (layer 0)
  const int lnb = ln * 512;       // fp16 plane: row byte base (row = mb*16+ln)
  const int lnb8 = ln * 256;      // lo8 plane

  for (int chunk = 0; chunk < 2; ++chunk){
    const int rbase = chunk << 6;

    // ---- layer 0: x(64x3) @ W0(3x256) + b0, relu -> hbuf hi fp16 / lo e5m2 (x256, swizzled)
    {
      float wa0 = W0[c],       wb0 = W0[c + 1];
      float wa1 = W0[256 + c], wb1 = W0[256 + c + 1];
      float wa2 = W0[512 + c], wb2 = W0[512 + c + 1];
      float ba = b0[c], bb = b0[c + 1];
      int r0 = (t >> 7) << 5;    // rows 0..31 or 32..63 (local)
      for (int r = r0; r < r0 + 32; ++r){
        int gr = rbase + r;
        float x0 = xls[gr * 3 + 0], x1 = xls[gr * 3 + 1], x2 = xls[gr * 3 + 2];
        float ha = fmaxf(fmaf(x2, wa2, fmaf(x1, wa1, fmaf(x0, wa0, ba))), 0.f) * 256.f;
        float hb = fmaxf(fmaf(x2, wb2, fmaf(x1, wb1, fmaf(x0, wb0, bb))), 0.f) * 256.f;
        _Float16 ah = (_Float16)ha, bh = (_Float16)hb;
        _Float16 al = (_Float16)(ha - (float)ah), bl = (_Float16)(hb - (float)bh);
        int offh = (r * 512 + c * 2) ^ ((r & 7) << 4);
        *(unsigned*)((char*)hbuf_hi + offh) = pack2(ah, bh);
        int off8 = r * 256 + (c ^ ((r & 7) << 3));
        unsigned short lo2 = (unsigned short)enc8(al) | ((unsigned short)enc8(bl) << 8);
        *(unsigned short*)(hbuf_l8 + off8) = lo2;
      }
    }
    __syncthreads();

    // ---- layers 1,2: h(64x256) @ W(256x256) + b, relu. fp16 split MFMA (3 per product)
    for (int L = 0; L < 2; ++L){
      const half8* Bh8 = (const half8*)(wsu + (L ? 131072 : 0));
      const half8* Bl8 = (const half8*)(wsu + (L ? 196608 : 65536));
      const float* bias = L ? b2 : b1;
      const int n0 = wv * 64;

      f32x4 acc[4][4];
      #pragma unroll
      for (int mb = 0; mb < 4; ++mb)
        #pragma unroll
        for (int nb = 0; nb < 4; ++nb)
          acc[mb][nb] = 0.f;

      #pragma unroll 1            // RUNTIME loop: bounds B live range to one kk
      for (int kk = 0; kk < 8; ++kk){
        const half8* Bhp = Bh8 + (kk * 4 + hi) * 256 + n0 + ln;
        const half8* Blp = Bl8 + (kk * 4 + hi) * 256 + n0 + ln;
        half8 Bhf[4], Blf[4];
        #pragma unroll
        for (int nb = 0; nb < 4; ++nb){
          Bhf[nb] = Bhp[nb * 16];
          Blf[nb] = Blp[nb * 16];
        }
        int kx  = lnb  + ((kk * 64 + hi * 16) ^ swzx);
        int kx8 = lnb8 + ((kk * 32 + hi * 8)  ^ swz8);
        #pragma unroll
        for (int mb = 0; mb < 4; ++mb){
          half8 Ahf = *(const half8*)((const char*)hbuf_hi + kx + mb * 8192);
          half8 Alf = dec8(*(const unsigned long long*)(hbuf_l8 + kx8 + mb * 4096));
          #pragma unroll
          for (int nb = 0; nb < 4; ++nb)
            acc[mb][nb] = __builtin_amdgcn_mfma_f32_16x16x32_f16(Ahf, Bhf[nb], acc[mb][nb], 0, 0, 0);
          #pragma unroll
          for (int nb = 0; nb < 4; ++nb)
            acc[mb][nb] = __builtin_amdgcn_mfma_f32_16x16x32_f16(Ahf, Blf[nb], acc[mb][nb], 0, 0, 0);
          #pragma unroll
          for (int nb = 0; nb < 4; ++nb)
            acc[mb][nb] = __builtin_amdgcn_mfma_f32_16x16x32_f16(Alf, Bhf[nb], acc[mb][nb], 0, 0, 0);
        }
      }

      float bv[4];
      #pragma unroll
      for (int nb = 0; nb < 4; ++nb) bv[nb] = bias[n0 + nb * 16 + ln];

      __syncthreads();   // all waves done reading hbuf before in-place overwrite
      #pragma unroll
      for (int mb = 0; mb < 4; ++mb){
        #pragma unroll
        for (int nb = 0; nb < 4; ++nb){
          int col = n0 + nb * 16 + ln;
          #pragma unroll
          for (int r = 0; r < 4; ++r){
            int row = mb * 16 + hi * 4 + r;
            float f = fmaxf(fmaf(acc[mb][nb][r], USC, bv[nb]), 0.f) * 256.f;
            _Float16 fh = (_Float16)f;
            _Float16 fl = (_Float16)(f - (float)fh);
            int offh = (row * 512 + col * 2) ^ ((row & 7) << 4);
            *(_Float16*)((char*)hbuf_hi + offh) = fh;
            int off8 = row * 256 + (col ^ ((row & 7) << 3));
            hbuf_l8[off8] = enc8(fl);
          }
        }
      }
      __syncthreads();
    }

    // ---- layer 3: h(64x256) @ W3(256x4) + b3 -> obuf f32 (N padded to 16)
    {
      const _Float16* B3hb = wsu + 262144;
      const _Float16* B3lb = wsu + 266240;
      f32x4 a3 = 0.f;
      #pragma unroll 1
      for (int kk = 0; kk < 8; ++kk){
        int bi = (kk * 4 + hi) * 16 + ln;
        half8 Bhf = ((const half8*)B3hb)[bi];
        half8 Blf = ((const half8*)B3lb)[bi];
        int kx  = lnb  + ((kk * 64 + hi * 16) ^ swzx) + wv * 8192;  // row = wv*16+ln
        int kx8 = lnb8 + ((kk * 32 + hi * 8)  ^ swz8) + wv * 4096;
        half8 Ah = *(const half8*)((const char*)hbuf_hi + kx);
        half8 Al = dec8(*(const unsigned long long*)(hbuf_l8 + kx8));
        a3 = __builtin_amdgcn_mfma_f32_16x16x32_f16(Ah, Bhf, a3, 0, 0, 0);
        a3 = __builtin_amdgcn_mfma_f32_16x16x32_f16(Ah, Blf, a3, 0, 0, 0);
        a3 = __builtin_amdgcn_mfma_f32_16x16x32_f16(Al, Bhf, a3, 0, 0, 0);
      }
      if (ln < 4){
        float b3v = b3[ln];
        #pragma unroll
        for (int r = 0; r < 4; ++r){
          int row = rbase + wv * 16 + hi * 4 + r;
          obuf[row * 4 + ln] = fmaf(a3[r], USC, b3v);
        }
      }
    }
    __syncthreads();   // L3 reads done before next chunk's layer-0 overwrites hbuf
  }

  // ---- epilogue: blend weights + outputs (threads 0..127 = waves 0,1)
  float inc = 1.f, alpha = 0.f, sig0 = 0.f, sig1 = 0.f, sig2 = 0.f;
  if (t < NSAMP){
    const float4* ov = (const float4*)obuf;
    float4 o = ov[t];
    sig0 = 1.f / (1.f + expf(-o.x));
    sig1 = 1.f / (1.f + expf(-o.y));
    sig2 = 1.f / (1.f + expf(-o.z));
    float op = (o.w > 20.f) ? o.w : log1pf(expf(o.w));
    float delta = (t < NSAMP - 1) ? (tl[t + 1] - tl[t]) : 1e10f;
    alpha = 1.f - expf(-op * delta);
    float u = fminf(1.f, 1.f - alpha + 1e-10f);
    inc = u;                               // inclusive product scan within wave
    #pragma unroll
    for (int off = 1; off < 64; off <<= 1){
      float v = __shfl_up(inc, off);
      if (lane >= off) inc *= v;
    }
    if (wv == 0 && lane == 63) stot = inc; // product of u[0..63]
  }
  __syncthreads();
  if (t < NSAMP){
    float ex = __shfl_up(inc, 1);
    if (lane == 0) ex = 1.f;
    if (wv == 1) ex *= stot;               // exclusive scan across waves
    float wgt = alpha * ex;
    float sr = wgt * sig0, sg = wgt * sig1, sb = wgt * sig2;
    float aw = (t < NSAMP - 1) ? wgt : 0.f;
    float wm = (t < NSAMP - 1) ? wgt : -1e30f;
    float wmv = wm;
    #pragma unroll
    for (int off = 32; off; off >>= 1){
      sr += __shfl_xor(sr, off);
      sg += __shfl_xor(sg, off);
      sb += __shfl_xor(sb, off);
      aw += __shfl_xor(aw, off);
      wm = fmaxf(wm, __shfl_xor(wm, off));
    }
    unsigned long long bal = __ballot(wmv == wm);
    int fi = __ffsll(bal) - 1;             // first max within wave
    if (lane == 0){
      redf[wv][0] = sr; redf[wv][1] = sg; redf[wv][2] = sb;
      redf[wv][3] = aw; redf[wv][4] = wm;
      redi[wv] = fi;
    }
  }
  __syncthreads();
  if (t == 0){
    float cr = redf[0][0] + redf[1][0];
    float cg = redf[0][1] + redf[1][1];
    float cb = redf[0][2] + redf[1][2];
    float asum = redf[0][3] + redf[1][3];
    int idx = (redf[1][4] > redf[0][4]) ? (64 + redi[1]) : redi[0]; // first max overall
    int cutoff = (asum < 0.1f) ? (NSAMP - 1) : idx;
    out[ray * 3 + 0] = cr;
    out[ray * 3 + 1] = cg;
    out[ray * 3 + 2] = cb;
    out[NRAYS * 3 + ray] = asum;
    out[NRAYS * 4 + ray] = tl[cutoff];
  }
}

extern "C" void kernel_launch(void* const* d_in, const int* in_sizes, int n_in,
                              void* d_out, int out_size, void* d_ws, size_t ws_size,
                              hipStream_t stream) {
  const float* pos = (const float*)d_in[0];
  const float* tv  = (const float*)d_in[1];
  const float* W0  = (const float*)d_in[2];
  const float* b0  = (const float*)d_in[3];
  const float* W1  = (const float*)d_in[4];
  const float* b1  = (const float*)d_in[5];
  const float* W2  = (const float*)d_in[6];
  const float* b2  = (const float*)d_in[7];
  const float* W3  = (const float*)d_in[8];
  const float* b3  = (const float*)d_in[9];
  _Float16* wsu = (_Float16*)d_ws;

  prep_kernel<<<528, 256, 0, stream>>>(W1, W2, W3, wsu);
  nerf_kernel<<<NRAYS, 256, 0, stream>>>(pos, tv, W0, b0, b1, b2, b3, wsu, (float*)d_out);
}

// Round 15
// 243.470 us; speedup vs baseline: 1.9130x; 1.9130x over previous
//
#include <hip/hip_runtime.h>

#define NRAYS 2048
#define NSAMP 128
#define HID   256

typedef __attribute__((ext_vector_type(8))) _Float16 half8;
typedef __attribute__((ext_vector_type(4))) float f32x4;

__device__ __forceinline__ unsigned pack2(_Float16 a, _Float16 b){
  unsigned short ua = __builtin_bit_cast(unsigned short, a);
  unsigned short ub = __builtin_bit_cast(unsigned short, b);
  return (unsigned)ua | ((unsigned)ub << 16);
}

// e5m2 byte: fp16 with bottom 8 mantissa bits dropped (same exponent field).
// encode = RNE round fp16 -> top byte; decode = byte<<8 reinterpreted as fp16.
__device__ __forceinline__ unsigned char enc8(_Float16 x){
  unsigned short h = __builtin_bit_cast(unsigned short, x);
  unsigned short r = (unsigned short)(h + 0x7F + ((h >> 8) & 1));
  return (unsigned char)(r >> 8);
}
__device__ __forceinline__ half8 dec8(unsigned long long v){
  half8 r;
  #pragma unroll
  for (int j = 0; j < 8; ++j){
    unsigned short u = (unsigned short)(((v >> (8 * j)) & 0xFFull) << 8);
    r[j] = __builtin_bit_cast(_Float16, u);
  }
  return r;
}

// ---- weight preprocess: fp32 row-major [K][N] -> fp16 hi/lo packed [K/8][N][8], scaled x256
// half offsets in ws: W1hi 0, W1lo 65536, W2hi 131072, W2lo 196608,
//                     W3hi 262144 (padded N=16, 4096), W3lo 266240
__global__ void prep_kernel(const float* __restrict__ W1,
                            const float* __restrict__ W2,
                            const float* __restrict__ W3,
                            _Float16* __restrict__ out)
{
  int idx = blockIdx.x * 256 + threadIdx.x;
  float v; int pk, base, lstep;
  if (idx < 65536){
    int k = idx >> 8, n = idx & 255;
    v = W1[idx] * 256.f; pk = (((k >> 3) << 8) + n) * 8 + (k & 7); base = 0; lstep = 65536;
  } else if (idx < 131072){
    int j = idx - 65536; int k = j >> 8, n = j & 255;
    v = W2[j] * 256.f; pk = (((k >> 3) << 8) + n) * 8 + (k & 7); base = 131072; lstep = 65536;
  } else if (idx < 135168){
    int j = idx - 131072;
    int n = (j >> 3) & 15;
    int k = ((j >> 7) << 3) | (j & 7);
    v = (n < 4) ? W3[k * 4 + n] * 256.f : 0.f; pk = j; base = 262144; lstep = 4096;
  } else return;
  _Float16 hi = (_Float16)v;
  _Float16 lo = (_Float16)(v - (float)hi);
  out[base + pk] = hi;
  out[base + lstep + pk] = lo;
}

// Two 64-sample chunks per ray. Activation tile: fp16 hi (32KB) + e5m2 lo (16KB)
// -> block LDS 53.76KB; 3 blocks fit per CU (161280 <= 163840 B).
// __launch_bounds__(256,2): the 128-VGPR cap r11 proved spill-free (116 used).
// (256,3) in r14 capped VGPR at 84 -> 760MB/dispatch scratch spill (post-mortem).
// Runtime occupancy is resource-driven: LDS allows 3 blocks, 3 waves/SIMD x 116
// VGPR = 348 <= 512 -> 12 waves/CU without spilling.
__launch_bounds__(256, 2)
__global__ void nerf_kernel(const float* __restrict__ pos,
                            const float* __restrict__ tvals,
                            const float* __restrict__ W0,
                            const float* __restrict__ b0,
                            const float* __restrict__ b1,
                            const float* __restrict__ b2,
                            const float* __restrict__ b3,
                            const _Float16* __restrict__ wsu,
                            float* __restrict__ out)
{
  __shared__ __align__(16) _Float16      hbuf_hi[64 * HID]; // 32 KB swizzled
  __shared__ __align__(16) unsigned char hbuf_l8[64 * HID]; // 16 KB swizzled e5m2
  __shared__ float xls[NSAMP * 3];
  __shared__ float tl[NSAMP];
  __shared__ __align__(16) float obuf[NSAMP * 4];
  __shared__ float stot;
  __shared__ float redf[2][5];
  __shared__ int   redi[2];

  const int t    = threadIdx.x;
  const int ray  = blockIdx.x;
  const int lane = t & 63;
  const int wv   = t >> 6;     // wave id 0..3
  const int ln   = lane & 15;
  const int hi   = lane >> 4;
  const int swzx = (ln & 7) << 4;   // fp16-plane swizzle (16B granules)
  const int swz8 = (ln & 7) << 3;   // lo8-plane swizzle (8B granules)
  const float USC = 1.f / 65536.f;

  // ---- stage inputs
  {
    const float* pbase = pos + (size_t)ray * NSAMP * 3;
    xls[t] = pbase[t];
    if (t < NSAMP) xls[256 + t] = pbase[256 + t];
    if (t < NSAMP) tl[t] = tvals[(size_t)ray * NSAMP + t];
  }
  __syncthreads();

  const int c = (t & 127) << 1;   // two adjacent cols per thread (layer 0)
  const int lnb = ln * 512;       // fp16 plane: row byte base (row = mb*16+ln)
  const int lnb8 = ln * 256;      // lo8 plane

  for (int chunk = 0; chunk < 2; ++chunk){
    const int rbase = chunk << 6;

    // ---- layer 0: x(64x3) @ W0(3x256) + b0, relu -> hbuf hi fp16 / lo e5m2 (x256, swizzled)
    {
      float wa0 = W0[c],       wb0 = W0[c + 1];
      float wa1 = W0[256 + c], wb1 = W0[256 + c + 1];
      float wa2 = W0[512 + c], wb2 = W0[512 + c + 1];
      float ba = b0[c], bb = b0[c + 1];
      int r0 = (t >> 7) << 5;    // rows 0..31 or 32..63 (local)
      for (int r = r0; r < r0 + 32; ++r){
        int gr = rbase + r;
        float x0 = xls[gr * 3 + 0], x1 = xls[gr * 3 + 1], x2 = xls[gr * 3 + 2];
        float ha = fmaxf(fmaf(x2, wa2, fmaf(x1, wa1, fmaf(x0, wa0, ba))), 0.f) * 256.f;
        float hb = fmaxf(fmaf(x2, wb2, fmaf(x1, wb1, fmaf(x0, wb0, bb))), 0.f) * 256.f;
        _Float16 ah = (_Float16)ha, bh = (_Float16)hb;
        _Float16 al = (_Float16)(ha - (float)ah), bl = (_Float16)(hb - (float)bh);
        int offh = (r * 512 + c * 2) ^ ((r & 7) << 4);
        *(unsigned*)((char*)hbuf_hi + offh) = pack2(ah, bh);
        int off8 = r * 256 + (c ^ ((r & 7) << 3));
        unsigned short lo2 = (unsigned short)enc8(al) | ((unsigned short)enc8(bl) << 8);
        *(unsigned short*)(hbuf_l8 + off8) = lo2;
      }
    }
    __syncthreads();

    // ---- layers 1,2: h(64x256) @ W(256x256) + b, relu. fp16 split MFMA (3 per product)
    for (int L = 0; L < 2; ++L){
      const half8* Bh8 = (const half8*)(wsu + (L ? 131072 : 0));
      const half8* Bl8 = (const half8*)(wsu + (L ? 196608 : 65536));
      const float* bias = L ? b2 : b1;
      const int n0 = wv * 64;

      f32x4 acc[4][4];
      #pragma unroll
      for (int mb = 0; mb < 4; ++mb)
        #pragma unroll
        for (int nb = 0; nb < 4; ++nb)
          acc[mb][nb] = 0.f;

      #pragma unroll 1            // RUNTIME loop: bounds B live range to one kk
      for (int kk = 0; kk < 8; ++kk){
        const half8* Bhp = Bh8 + (kk * 4 + hi) * 256 + n0 + ln;
        const half8* Blp = Bl8 + (kk * 4 + hi) * 256 + n0 + ln;
        half8 Bhf[4], Blf[4];
        #pragma unroll
        for (int nb = 0; nb < 4; ++nb){
          Bhf[nb] = Bhp[nb * 16];
          Blf[nb] = Blp[nb * 16];
        }
        int kx  = lnb  + ((kk * 64 + hi * 16) ^ swzx);
        int kx8 = lnb8 + ((kk * 32 + hi * 8)  ^ swz8);
        #pragma unroll
        for (int mb = 0; mb < 4; ++mb){
          half8 Ahf = *(const half8*)((const char*)hbuf_hi + kx + mb * 8192);
          half8 Alf = dec8(*(const unsigned long long*)(hbuf_l8 + kx8 + mb * 4096));
          #pragma unroll
          for (int nb = 0; nb < 4; ++nb)
            acc[mb][nb] = __builtin_amdgcn_mfma_f32_16x16x32_f16(Ahf, Bhf[nb], acc[mb][nb], 0, 0, 0);
          #pragma unroll
          for (int nb = 0; nb < 4; ++nb)
            acc[mb][nb] = __builtin_amdgcn_mfma_f32_16x16x32_f16(Ahf, Blf[nb], acc[mb][nb], 0, 0, 0);
          #pragma unroll
          for (int nb = 0; nb < 4; ++nb)
            acc[mb][nb] = __builtin_amdgcn_mfma_f32_16x16x32_f16(Alf, Bhf[nb], acc[mb][nb], 0, 0, 0);
        }
      }

      float bv[4];
      #pragma unroll
      for (int nb = 0; nb < 4; ++nb) bv[nb] = bias[n0 + nb * 16 + ln];

      __syncthreads();   // all waves done reading hbuf before in-place overwrite
      #pragma unroll
      for (int mb = 0; mb < 4; ++mb){
        #pragma unroll
        for (int nb = 0; nb < 4; ++nb){
          int col = n0 + nb * 16 + ln;
          #pragma unroll
          for (int r = 0; r < 4; ++r){
            int row = mb * 16 + hi * 4 + r;
            float f = fmaxf(fmaf(acc[mb][nb][r], USC, bv[nb]), 0.f) * 256.f;
            _Float16 fh = (_Float16)f;
            _Float16 fl = (_Float16)(f - (float)fh);
            int offh = (row * 512 + col * 2) ^ ((row & 7) << 4);
            *(_Float16*)((char*)hbuf_hi + offh) = fh;
            int off8 = row * 256 + (col ^ ((row & 7) << 3));
            hbuf_l8[off8] = enc8(fl);
          }
        }
      }
      __syncthreads();
    }

    // ---- layer 3: h(64x256) @ W3(256x4) + b3 -> obuf f32 (N padded to 16)
    {
      const _Float16* B3hb = wsu + 262144;
      const _Float16* B3lb = wsu + 266240;
      f32x4 a3 = 0.f;
      #pragma unroll 1
      for (int kk = 0; kk < 8; ++kk){
        int bi = (kk * 4 + hi) * 16 + ln;
        half8 Bhf = ((const half8*)B3hb)[bi];
        half8 Blf = ((const half8*)B3lb)[bi];
        int kx  = lnb  + ((kk * 64 + hi * 16) ^ swzx) + wv * 8192;  // row = wv*16+ln
        int kx8 = lnb8 + ((kk * 32 + hi * 8)  ^ swz8) + wv * 4096;
        half8 Ah = *(const half8*)((const char*)hbuf_hi + kx);
        half8 Al = dec8(*(const unsigned long long*)(hbuf_l8 + kx8));
        a3 = __builtin_amdgcn_mfma_f32_16x16x32_f16(Ah, Bhf, a3, 0, 0, 0);
        a3 = __builtin_amdgcn_mfma_f32_16x16x32_f16(Ah, Blf, a3, 0, 0, 0);
        a3 = __builtin_amdgcn_mfma_f32_16x16x32_f16(Al, Bhf, a3, 0, 0, 0);
      }
      if (ln < 4){
        float b3v = b3[ln];
        #pragma unroll
        for (int r = 0; r < 4; ++r){
          int row = rbase + wv * 16 + hi * 4 + r;
          obuf[row * 4 + ln] = fmaf(a3[r], USC, b3v);
        }
      }
    }
    __syncthreads();   // L3 reads done before next chunk's layer-0 overwrites hbuf
  }

  // ---- epilogue: blend weights + outputs (threads 0..127 = waves 0,1)
  float inc = 1.f, alpha = 0.f, sig0 = 0.f, sig1 = 0.f, sig2 = 0.f;
  if (t < NSAMP){
    const float4* ov = (const float4*)obuf;
    float4 o = ov[t];
    sig0 = 1.f / (1.f + expf(-o.x));
    sig1 = 1.f / (1.f + expf(-o.y));
    sig2 = 1.f / (1.f + expf(-o.z));
    float op = (o.w > 20.f) ? o.w : log1pf(expf(o.w));
    float delta = (t < NSAMP - 1) ? (tl[t + 1] - tl[t]) : 1e10f;
    alpha = 1.f - expf(-op * delta);
    float u = fminf(1.f, 1.f - alpha + 1e-10f);
    inc = u;                               // inclusive product scan within wave
    #pragma unroll
    for (int off = 1; off < 64; off <<= 1){
      float v = __shfl_up(inc, off);
      if (lane >= off) inc *= v;
    }
    if (wv == 0 && lane == 63) stot = inc; // product of u[0..63]
  }
  __syncthreads();
  if (t < NSAMP){
    float ex = __shfl_up(inc, 1);
    if (lane == 0) ex = 1.f;
    if (wv == 1) ex *= stot;               // exclusive scan across waves
    float wgt = alpha * ex;
    float sr = wgt * sig0, sg = wgt * sig1, sb = wgt * sig2;
    float aw = (t < NSAMP - 1) ? wgt : 0.f;
    float wm = (t < NSAMP - 1) ? wgt : -1e30f;
    float wmv = wm;
    #pragma unroll
    for (int off = 32; off; off >>= 1){
      sr += __shfl_xor(sr, off);
      sg += __shfl_xor(sg, off);
      sb += __shfl_xor(sb, off);
      aw += __shfl_xor(aw, off);
      wm = fmaxf(wm, __shfl_xor(wm, off));
    }
    unsigned long long bal = __ballot(wmv == wm);
    int fi = __ffsll(bal) - 1;             // first max within wave
    if (lane == 0){
      redf[wv][0] = sr; redf[wv][1] = sg; redf[wv][2] = sb;
      redf[wv][3] = aw; redf[wv][4] = wm;
      redi[wv] = fi;
    }
  }
  __syncthreads();
  if (t == 0){
    float cr = redf[0][0] + redf[1][0];
    float cg = redf[0][1] + redf[1][1];
    float cb = redf[0][2] + redf[1][2];
    float asum = redf[0][3] + redf[1][3];
    int idx = (redf[1][4] > redf[0][4]) ? (64 + redi[1]) : redi[0]; // first max overall
    int cutoff = (asum < 0.1f) ? (NSAMP - 1) : idx;
    out[ray * 3 + 0] = cr;
    out[ray * 3 + 1] = cg;
    out[ray * 3 + 2] = cb;
    out[NRAYS * 3 + ray] = asum;
    out[NRAYS * 4 + ray] = tl[cutoff];
  }
}

extern "C" void kernel_launch(void* const* d_in, const int* in_sizes, int n_in,
                              void* d_out, int out_size, void* d_ws, size_t ws_size,
                              hipStream_t stream) {
  const float* pos = (const float*)d_in[0];
  const float* tv  = (const float*)d_in[1];
  const float* W0  = (const float*)d_in[2];
  const float* b0  = (const float*)d_in[3];
  const float* W1  = (const float*)d_in[4];
  const float* b1  = (const float*)d_in[5];
  const float* W2  = (const float*)d_in[6];
  const float* b2  = (const float*)d_in[7];
  const float* W3  = (const float*)d_in[8];
  const float* b3  = (const float*)d_in[9];
  _Float16* wsu = (_Float16*)d_ws;

  prep_kernel<<<528, 256, 0, stream>>>(W1, W2, W3, wsu);
  nerf_kernel<<<NRAYS, 256, 0, stream>>>(pos, tv, W0, b0, b1, b2, b3, wsu, (float*)d_out);
}

// Round 16
// 243.354 us; speedup vs baseline: 1.9139x; 1.0005x over previous
//
#include <hip/hip_runtime.h>

#define NRAYS 2048
#define NSAMP 128
#define HID   256

typedef __attribute__((ext_vector_type(8))) _Float16 half8;
typedef __attribute__((ext_vector_type(4))) float f32x4;
typedef __attribute__((ext_vector_type(4))) unsigned u32x4;

__device__ __forceinline__ unsigned pack2(_Float16 a, _Float16 b){
  unsigned short ua = __builtin_bit_cast(unsigned short, a);
  unsigned short ub = __builtin_bit_cast(unsigned short, b);
  return (unsigned)ua | ((unsigned)ub << 16);
}

// e5m2 byte: fp16 with bottom 8 mantissa bits dropped (same exponent field).
// encode = RNE round fp16 -> top byte; decode = byte<<8 reinterpreted as fp16.
__device__ __forceinline__ unsigned char enc8(_Float16 x){
  unsigned short h = __builtin_bit_cast(unsigned short, x);
  unsigned short r = (unsigned short)(h + 0x7F + ((h >> 8) & 1));
  return (unsigned char)(r >> 8);
}
// dword-wise decode: 8 bytes -> 4 dwords of 2 fp16 each (b<<8 per half)
__device__ __forceinline__ half8 dec8(unsigned long long v){
  unsigned a = (unsigned)v, b = (unsigned)(v >> 32);
  u32x4 d;
  d[0] = ((a & 0x000000FFu) << 8)  | ((a & 0x0000FF00u) << 16);
  d[1] = ((a & 0x00FF0000u) >> 8)  |  (a & 0xFF000000u);
  d[2] = ((b & 0x000000FFu) << 8)  | ((b & 0x0000FF00u) << 16);
  d[3] = ((b & 0x00FF0000u) >> 8)  |  (b & 0xFF000000u);
  return __builtin_bit_cast(half8, d);
}

// ---- weight preprocess: fp32 row-major [K][N] -> fp16 hi/lo packed [K/8][N][8], scaled x256
// half offsets in ws: W1hi 0, W1lo 65536, W2hi 131072, W2lo 196608,
//                     W3hi 262144 (padded N=16, 4096), W3lo 266240
__global__ void prep_kernel(const float* __restrict__ W1,
                            const float* __restrict__ W2,
                            const float* __restrict__ W3,
                            _Float16* __restrict__ out)
{
  int idx = blockIdx.x * 256 + threadIdx.x;
  float v; int pk, base, lstep;
  if (idx < 65536){
    int k = idx >> 8, n = idx & 255;
    v = W1[idx] * 256.f; pk = (((k >> 3) << 8) + n) * 8 + (k & 7); base = 0; lstep = 65536;
  } else if (idx < 131072){
    int j = idx - 65536; int k = j >> 8, n = j & 255;
    v = W2[j] * 256.f; pk = (((k >> 3) << 8) + n) * 8 + (k & 7); base = 131072; lstep = 65536;
  } else if (idx < 135168){
    int j = idx - 131072;
    int n = (j >> 3) & 15;
    int k = ((j >> 7) << 3) | (j & 7);
    v = (n < 4) ? W3[k * 4 + n] * 256.f : 0.f; pk = j; base = 262144; lstep = 4096;
  } else return;
  _Float16 hi = (_Float16)v;
  _Float16 lo = (_Float16)(v - (float)hi);
  out[base + pk] = hi;
  out[base + lstep + pk] = lo;
}

// Two 64-sample chunks per ray. Activation tile: fp16 hi (32KB) + e5m2 lo (16KB)
// -> block LDS 53.76KB; 3 blocks/CU by LDS (161280 <= 163840 B).
// (256,2) = the spill-free 128-VGPR cap. r15 spilled (~100MB) because 32 live
// B-regs + dec8 temps crossed 128. Fix: two B-passes per kk (Bhi then Blo,
// sched_barrier(0) fence) -> B liveness 16 regs; dword-wise dec8 -> fewer temps.
__launch_bounds__(256, 2)
__global__ void nerf_kernel(const float* __restrict__ pos,
                            const float* __restrict__ tvals,
                            const float* __restrict__ W0,
                            const float* __restrict__ b0,
                            const float* __restrict__ b1,
                            const float* __restrict__ b2,
                            const float* __restrict__ b3,
                            const _Float16* __restrict__ wsu,
                            float* __restrict__ out)
{
  __shared__ __align__(16) _Float16      hbuf_hi[64 * HID]; // 32 KB swizzled
  __shared__ __align__(16) unsigned char hbuf_l8[64 * HID]; // 16 KB swizzled e5m2
  __shared__ float xls[NSAMP * 3];
  __shared__ float tl[NSAMP];
  __shared__ __align__(16) float obuf[NSAMP * 4];
  __shared__ float stot;
  __shared__ float redf[2][5];
  __shared__ int   redi[2];

  const int t    = threadIdx.x;
  const int ray  = blockIdx.x;
  const int lane = t & 63;
  const int wv   = t >> 6;     // wave id 0..3
  const int ln   = lane & 15;
  const int hi   = lane >> 4;
  const int swzx = (ln & 7) << 4;   // fp16-plane swizzle (16B granules)
  const int swz8 = (ln & 7) << 3;   // lo8-plane swizzle (8B granules)
  const float USC = 1.f / 65536.f;

  // ---- stage inputs
  {
    const float* pbase = pos + (size_t)ray * NSAMP * 3;
    xls[t] = pbase[t];
    if (t < NSAMP) xls[256 + t] = pbase[256 + t];
    if (t < NSAMP) tl[t] = tvals[(size_t)ray * NSAMP + t];
  }
  __syncthreads();

  const int c = (t & 127) << 1;   // two adjacent cols per thread (layer 0)
  const int lnb = ln * 512;       // fp16 plane: row byte base (row = mb*16+ln)
  const int lnb8 = ln * 256;      // lo8 plane

  for (int chunk = 0; chunk < 2; ++chunk){
    const int rbase = chunk << 6;

    // ---- layer 0: x(64x3) @ W0(3x256) + b0, relu -> hbuf hi fp16 / lo e5m2 (x256, swizzled)
    {
      float wa0 = W0[c],       wb0 = W0[c + 1];
      float wa1 = W0[256 + c], wb1 = W0[256 + c + 1];
      float wa2 = W0[512 + c], wb2 = W0[512 + c + 1];
      float ba = b0[c], bb = b0[c + 1];
      int r0 = (t >> 7) << 5;    // rows 0..31 or 32..63 (local)
      for (int r = r0; r < r0 + 32; ++r){
        int gr = rbase + r;
        float x0 = xls[gr * 3 + 0], x1 = xls[gr * 3 + 1], x2 = xls[gr * 3 + 2];
        float ha = fmaxf(fmaf(x2, wa2, fmaf(x1, wa1, fmaf(x0, wa0, ba))), 0.f) * 256.f;
        float hb = fmaxf(fmaf(x2, wb2, fmaf(x1, wb1, fmaf(x0, wb0, bb))), 0.f) * 256.f;
        _Float16 ah = (_Float16)ha, bh = (_Float16)hb;
        _Float16 al = (_Float16)(ha - (float)ah), bl = (_Float16)(hb - (float)bh);
        int offh = (r * 512 + c * 2) ^ ((r & 7) << 4);
        *(unsigned*)((char*)hbuf_hi + offh) = pack2(ah, bh);
        int off8 = r * 256 + (c ^ ((r & 7) << 3));
        unsigned short lo2 = (unsigned short)enc8(al) | ((unsigned short)enc8(bl) << 8);
        *(unsigned short*)(hbuf_l8 + off8) = lo2;
      }
    }
    __syncthreads();

    // ---- layers 1,2: h(64x256) @ W(256x256) + b, relu. fp16 split MFMA (3 per product)
    for (int L = 0; L < 2; ++L){
      const half8* Bh8 = (const half8*)(wsu + (L ? 131072 : 0));
      const half8* Bl8 = (const half8*)(wsu + (L ? 196608 : 65536));
      const float* bias = L ? b2 : b1;
      const int n0 = wv * 64;

      f32x4 acc[4][4];
      #pragma unroll
      for (int mb = 0; mb < 4; ++mb)
        #pragma unroll
        for (int nb = 0; nb < 4; ++nb)
          acc[mb][nb] = 0.f;

      #pragma unroll 1            // RUNTIME loop: bounds B live range to one kk
      for (int kk = 0; kk < 8; ++kk){
        const half8* Bhp = Bh8 + (kk * 4 + hi) * 256 + n0 + ln;
        const half8* Blp = Bl8 + (kk * 4 + hi) * 256 + n0 + ln;
        int kx  = lnb  + ((kk * 64 + hi * 16) ^ swzx);
        int kx8 = lnb8 + ((kk * 32 + hi * 8)  ^ swz8);

        half8 Bf[4];
        // ---- pass 1: B = Whi; terms Ahi*Bhi and Alo*Bhi (32 MFMAs)
        #pragma unroll
        for (int nb = 0; nb < 4; ++nb) Bf[nb] = Bhp[nb * 16];
        #pragma unroll
        for (int mb = 0; mb < 4; ++mb){
          half8 Ahf = *(const half8*)((const char*)hbuf_hi + kx + mb * 8192);
          half8 Alf = dec8(*(const unsigned long long*)(hbuf_l8 + kx8 + mb * 4096));
          #pragma unroll
          for (int nb = 0; nb < 4; ++nb)
            acc[mb][nb] = __builtin_amdgcn_mfma_f32_16x16x32_f16(Ahf, Bf[nb], acc[mb][nb], 0, 0, 0);
          #pragma unroll
          for (int nb = 0; nb < 4; ++nb)
            acc[mb][nb] = __builtin_amdgcn_mfma_f32_16x16x32_f16(Alf, Bf[nb], acc[mb][nb], 0, 0, 0);
        }
        __builtin_amdgcn_sched_barrier(0);   // fence: Blo loads stay below pass 1
        // ---- pass 2: B = Wlo; term Ahi*Blo (16 MFMAs; Ahi re-read from LDS)
        #pragma unroll
        for (int nb = 0; nb < 4; ++nb) Bf[nb] = Blp[nb * 16];
        #pragma unroll
        for (int mb = 0; mb < 4; ++mb){
          half8 Ahf = *(const half8*)((const char*)hbuf_hi + kx + mb * 8192);
          #pragma unroll
          for (int nb = 0; nb < 4; ++nb)
            acc[mb][nb] = __builtin_amdgcn_mfma_f32_16x16x32_f16(Ahf, Bf[nb], acc[mb][nb], 0, 0, 0);
        }
      }

      float bv[4];
      #pragma unroll
      for (int nb = 0; nb < 4; ++nb) bv[nb] = bias[n0 + nb * 16 + ln];

      __syncthreads();   // all waves done reading hbuf before in-place overwrite
      #pragma unroll
      for (int mb = 0; mb < 4; ++mb){
        #pragma unroll
        for (int nb = 0; nb < 4; ++nb){
          int col = n0 + nb * 16 + ln;
          #pragma unroll
          for (int r = 0; r < 4; ++r){
            int row = mb * 16 + hi * 4 + r;
            float f = fmaxf(fmaf(acc[mb][nb][r], USC, bv[nb]), 0.f) * 256.f;
            _Float16 fh = (_Float16)f;
            _Float16 fl = (_Float16)(f - (float)fh);
            int offh = (row * 512 + col * 2) ^ ((row & 7) << 4);
            *(_Float16*)((char*)hbuf_hi + offh) = fh;
            int off8 = row * 256 + (col ^ ((row & 7) << 3));
            hbuf_l8[off8] = enc8(fl);
          }
        }
      }
      __syncthreads();
    }

    // ---- layer 3: h(64x256) @ W3(256x4) + b3 -> obuf f32 (N padded to 16)
    {
      const _Float16* B3hb = wsu + 262144;
      const _Float16* B3lb = wsu + 266240;
      f32x4 a3 = 0.f;
      #pragma unroll 1
      for (int kk = 0; kk < 8; ++kk){
        int bi = (kk * 4 + hi) * 16 + ln;
        half8 Bhf = ((const half8*)B3hb)[bi];
        half8 Blf = ((const half8*)B3lb)[bi];
        int kx  = lnb  + ((kk * 64 + hi * 16) ^ swzx) + wv * 8192;  // row = wv*16+ln
        int kx8 = lnb8 + ((kk * 32 + hi * 8)  ^ swz8) + wv * 4096;
        half8 Ah = *(const half8*)((const char*)hbuf_hi + kx);
        half8 Al = dec8(*(const unsigned long long*)(hbuf_l8 + kx8));
        a3 = __builtin_amdgcn_mfma_f32_16x16x32_f16(Ah, Bhf, a3, 0, 0, 0);
        a3 = __builtin_amdgcn_mfma_f32_16x16x32_f16(Ah, Blf, a3, 0, 0, 0);
        a3 = __builtin_amdgcn_mfma_f32_16x16x32_f16(Al, Bhf, a3, 0, 0, 0);
      }
      if (ln < 4){
        float b3v = b3[ln];
        #pragma unroll
        for (int r = 0; r < 4; ++r){
          int row = rbase + wv * 16 + hi * 4 + r;
          obuf[row * 4 + ln] = fmaf(a3[r], USC, b3v);
        }
      }
    }
    __syncthreads();   // L3 reads done before next chunk's layer-0 overwrites hbuf
  }

  // ---- epilogue: blend weights + outputs (threads 0..127 = waves 0,1)
  float inc = 1.f, alpha = 0.f, sig0 = 0.f, sig1 = 0.f, sig2 = 0.f;
  if (t < NSAMP){
    const float4* ov = (const float4*)obuf;
    float4 o = ov[t];
    sig0 = 1.f / (1.f + expf(-o.x));
    sig1 = 1.f / (1.f + expf(-o.y));
    sig2 = 1.f / (1.f + expf(-o.z));
    float op = (o.w > 20.f) ? o.w : log1pf(expf(o.w));
    float delta = (t < NSAMP - 1) ? (tl[t + 1] - tl[t]) : 1e10f;
    alpha = 1.f - expf(-op * delta);
    float u = fminf(1.f, 1.f - alpha + 1e-10f);
    inc = u;                               // inclusive product scan within wave
    #pragma unroll
    for (int off = 1; off < 64; off <<= 1){
      float v = __shfl_up(inc, off);
      if (lane >= off) inc *= v;
    }
    if (wv == 0 && lane == 63) stot = inc; // product of u[0..63]
  }
  __syncthreads();
  if (t < NSAMP){
    float ex = __shfl_up(inc, 1);
    if (lane == 0) ex = 1.f;
    if (wv == 1) ex *= stot;               // exclusive scan across waves
    float wgt = alpha * ex;
    float sr = wgt * sig0, sg = wgt * sig1, sb = wgt * sig2;
    float aw = (t < NSAMP - 1) ? wgt : 0.f;
    float wm = (t < NSAMP - 1) ? wgt : -1e30f;
    float wmv = wm;
    #pragma unroll
    for (int off = 32; off; off >>= 1){
      sr += __shfl_xor(sr, off);
      sg += __shfl_xor(sg, off);
      sb += __shfl_xor(sb, off);
      aw += __shfl_xor(aw, off);
      wm = fmaxf(wm, __shfl_xor(wm, off));
    }
    unsigned long long bal = __ballot(wmv == wm);
    int fi = __ffsll(bal) - 1;             // first max within wave
    if (lane == 0){
      redf[wv][0] = sr; redf[wv][1] = sg; redf[wv][2] = sb;
      redf[wv][3] = aw; redf[wv][4] = wm;
      redi[wv] = fi;
    }
  }
  __syncthreads();
  if (t == 0){
    float cr = redf[0][0] + redf[1][0];
    float cg = redf[0][1] + redf[1][1];
    float cb = redf[0][2] + redf[1][2];
    float asum = redf[0][3] + redf[1][3];
    int idx = (redf[1][4] > redf[0][4]) ? (64 + redi[1]) : redi[0]; // first max overall
    int cutoff = (asum < 0.1f) ? (NSAMP - 1) : idx;
    out[ray * 3 + 0] = cr;
    out[ray * 3 + 1] = cg;
    out[ray * 3 + 2] = cb;
    out[NRAYS * 3 + ray] = asum;
    out[NRAYS * 4 + ray] = tl[cutoff];
  }
}

extern "C" void kernel_launch(void* const* d_in, const int* in_sizes, int n_in,
                              void* d_out, int out_size, void* d_ws, size_t ws_size,
                              hipStream_t stream) {
  const float* pos = (const float*)d_in[0];
  const float* tv  = (const float*)d_in[1];
  const float* W0  = (const float*)d_in[2];
  const float* b0  = (const float*)d_in[3];
  const float* W1  = (const float*)d_in[4];
  const float* b1  = (const float*)d_in[5];
  const float* W2  = (const float*)d_in[6];
  const float* b2  = (const float*)d_in[7];
  const float* W3  = (const float*)d_in[8];
  const float* b3  = (const float*)d_in[9];
  _Float16* wsu = (_Float16*)d_ws;

  prep_kernel<<<528, 256, 0, stream>>>(W1, W2, W3, wsu);
  nerf_kernel<<<NRAYS, 256, 0, stream>>>(pos, tv, W0, b0, b1, b2, b3, wsu, (float*)d_out);
}

// Round 17
// 232.309 us; speedup vs baseline: 2.0049x; 1.0475x over previous
//
#include <hip/hip_runtime.h>

#define NRAYS 2048
#define NSAMP 128
#define HID   256
#define CROWS 48   // rows per chunk (3 chunks; last has 16 zero-pad rows)

typedef __attribute__((ext_vector_type(8))) _Float16 half8;
typedef __attribute__((ext_vector_type(4))) float f32x4;

__device__ __forceinline__ unsigned pack2(_Float16 a, _Float16 b){
  unsigned short ua = __builtin_bit_cast(unsigned short, a);
  unsigned short ub = __builtin_bit_cast(unsigned short, b);
  return (unsigned)ua | ((unsigned)ub << 16);
}

// ---- weight preprocess: fp32 row-major [K][N] -> fp16 hi/lo packed [K/8][N][8], scaled x256
// half offsets in ws: W1hi 0, W1lo 65536, W2hi 131072, W2lo 196608,
//                     W3hi 262144 (padded N=16, 4096), W3lo 266240
__global__ void prep_kernel(const float* __restrict__ W1,
                            const float* __restrict__ W2,
                            const float* __restrict__ W3,
                            _Float16* __restrict__ out)
{
  int idx = blockIdx.x * 256 + threadIdx.x;
  float v; int pk, base, lstep;
  if (idx < 65536){
    int k = idx >> 8, n = idx & 255;
    v = W1[idx] * 256.f; pk = (((k >> 3) << 8) + n) * 8 + (k & 7); base = 0; lstep = 65536;
  } else if (idx < 131072){
    int j = idx - 65536; int k = j >> 8, n = j & 255;
    v = W2[j] * 256.f; pk = (((k >> 3) << 8) + n) * 8 + (k & 7); base = 131072; lstep = 65536;
  } else if (idx < 135168){
    int j = idx - 131072;
    int n = (j >> 3) & 15;
    int k = ((j >> 7) << 3) | (j & 7);
    v = (n < 4) ? W3[k * 4 + n] * 256.f : 0.f; pk = j; base = 262144; lstep = 4096;
  } else return;
  _Float16 hi = (_Float16)v;
  _Float16 lo = (_Float16)(v - (float)hi);
  out[base + pk] = hi;
  out[base + lstep + pk] = lo;
}

// Three 48-row chunks per ray (rows 96..143 zero-padded). Activation tile fp16
// hi+lo = 48KB; block LDS ~53.4KB -> 3 blocks/CU by LDS (3x53.76KB=161.3 <= 163.8KB).
// (256,2) keeps the spill-free 128-VGPR cap (r11 inner loop, acc 3x4=48 regs,
// live ~105). 12 waves/CU. e5m2 lo-plane abandoned (r15/r16: spills at cap).
__launch_bounds__(256, 2)
__global__ void nerf_kernel(const float* __restrict__ pos,
                            const float* __restrict__ tvals,
                            const float* __restrict__ W0,
                            const float* __restrict__ b0,
                            const float* __restrict__ b1,
                            const float* __restrict__ b2,
                            const float* __restrict__ b3,
                            const _Float16* __restrict__ wsu,
                            float* __restrict__ out)
{
  __shared__ __align__(16) _Float16 hbuf_hi[CROWS * HID]; // 24 KB swizzled
  __shared__ __align__(16) _Float16 hbuf_lo[CROWS * HID]; // 24 KB swizzled
  __shared__ float xls[NSAMP * 3];
  __shared__ float tl[NSAMP];
  __shared__ __align__(16) float obuf[NSAMP * 4];
  __shared__ float stot;
  __shared__ float redf[2][5];
  __shared__ int   redi[2];

  const int t    = threadIdx.x;
  const int ray  = blockIdx.x;
  const int lane = t & 63;
  const int wv   = t >> 6;     // wave id 0..3
  const int ln   = lane & 15;
  const int hi   = lane >> 4;
  const int swzx = (ln & 7) << 4;
  const float USC = 1.f / 65536.f;

  // ---- stage inputs
  {
    const float* pbase = pos + (size_t)ray * NSAMP * 3;
    xls[t] = pbase[t];
    if (t < NSAMP) xls[256 + t] = pbase[256 + t];
    if (t < NSAMP) tl[t] = tvals[(size_t)ray * NSAMP + t];
  }
  __syncthreads();

  const int c = (t & 127) << 1;   // two adjacent cols per thread (layer 0)
  const int lnb = ln * 512;       // row byte base (row = mb*16+ln -> +mb*8192)

  for (int chunk = 0; chunk < 3; ++chunk){
    const int rbase = chunk * CROWS;

    // ---- layer 0: x(48x3) @ W0(3x256) + b0, relu -> hbuf hi/lo (x256, swizzled)
    {
      float wa0 = W0[c],       wb0 = W0[c + 1];
      float wa1 = W0[256 + c], wb1 = W0[256 + c + 1];
      float wa2 = W0[512 + c], wb2 = W0[512 + c + 1];
      float ba = b0[c], bb = b0[c + 1];
      int r0 = (t >> 7) * 24;    // rows 0..23 or 24..47 (local)
      for (int r = r0; r < r0 + 24; ++r){
        int gr = rbase + r;
        float ha = 0.f, hb = 0.f;
        if (gr < NSAMP){         // pad rows (128..143) -> zeros (deterministic)
          float x0 = xls[gr * 3 + 0], x1 = xls[gr * 3 + 1], x2 = xls[gr * 3 + 2];
          ha = fmaxf(fmaf(x2, wa2, fmaf(x1, wa1, fmaf(x0, wa0, ba))), 0.f) * 256.f;
          hb = fmaxf(fmaf(x2, wb2, fmaf(x1, wb1, fmaf(x0, wb0, bb))), 0.f) * 256.f;
        }
        _Float16 ah = (_Float16)ha, bh = (_Float16)hb;
        _Float16 al = (_Float16)(ha - (float)ah), bl = (_Float16)(hb - (float)bh);
        int off = (r * 512 + c * 2) ^ ((r & 7) << 4);
        *(unsigned*)((char*)hbuf_hi + off) = pack2(ah, bh);
        *(unsigned*)((char*)hbuf_lo + off) = pack2(al, bl);
      }
    }
    __syncthreads();

    // ---- layers 1,2: h(48x256) @ W(256x256) + b, relu. fp16 split MFMA (3 per product)
    for (int L = 0; L < 2; ++L){
      const _Float16* Bhb = wsu + (L ? 131072 : 0);
      const _Float16* Blb = wsu + (L ? 196608 : 65536);
      const float* bias = L ? b2 : b1;
      const int n0 = wv * 64;

      f32x4 acc[3][4];
      #pragma unroll
      for (int mb = 0; mb < 3; ++mb)
        #pragma unroll
        for (int nb = 0; nb < 4; ++nb)
          acc[mb][nb] = 0.f;

      #pragma unroll 1            // RUNTIME loop: prevents B-load hoisting across kk
      for (int kk = 0; kk < 8; ++kk){
        const half8* Bhp = (const half8*)Bhb + (kk * 4 + hi) * 256 + n0 + ln;
        const half8* Blp = (const half8*)Blb + (kk * 4 + hi) * 256 + n0 + ln;
        half8 Bhf[4], Blf[4];
        #pragma unroll
        for (int nb = 0; nb < 4; ++nb){
          Bhf[nb] = Bhp[nb * 16];
          Blf[nb] = Blp[nb * 16];
        }
        int kx = lnb + ((kk * 64 + hi * 16) ^ swzx);
        #pragma unroll
        for (int mb = 0; mb < 3; ++mb){
          half8 Ahf = *(const half8*)((const char*)hbuf_hi + kx + mb * 8192);
          half8 Alf = *(const half8*)((const char*)hbuf_lo + kx + mb * 8192);
          #pragma unroll
          for (int nb = 0; nb < 4; ++nb)
            acc[mb][nb] = __builtin_amdgcn_mfma_f32_16x16x32_f16(Ahf, Bhf[nb], acc[mb][nb], 0, 0, 0);
          #pragma unroll
          for (int nb = 0; nb < 4; ++nb)
            acc[mb][nb] = __builtin_amdgcn_mfma_f32_16x16x32_f16(Ahf, Blf[nb], acc[mb][nb], 0, 0, 0);
          #pragma unroll
          for (int nb = 0; nb < 4; ++nb)
            acc[mb][nb] = __builtin_amdgcn_mfma_f32_16x16x32_f16(Alf, Bhf[nb], acc[mb][nb], 0, 0, 0);
        }
      }

      float bv[4];
      #pragma unroll
      for (int nb = 0; nb < 4; ++nb) bv[nb] = bias[n0 + nb * 16 + ln];

      __syncthreads();   // all waves done reading hbuf before in-place overwrite
      #pragma unroll
      for (int mb = 0; mb < 3; ++mb){
        #pragma unroll
        for (int nb = 0; nb < 4; ++nb){
          int col = n0 + nb * 16 + ln;
          #pragma unroll
          for (int r = 0; r < 4; ++r){
            int row = mb * 16 + hi * 4 + r;
            float f = fmaxf(fmaf(acc[mb][nb][r], USC, bv[nb]), 0.f) * 256.f;
            _Float16 fh = (_Float16)f;
            _Float16 fl = (_Float16)(f - (float)fh);
            int off = (row * 512 + col * 2) ^ ((row & 7) << 4);
            *(_Float16*)((char*)hbuf_hi + off) = fh;
            *(_Float16*)((char*)hbuf_lo + off) = fl;
          }
        }
      }
      __syncthreads();
    }

    // ---- layer 3: h(48x256) @ W3(256x4) + b3 -> obuf f32 (waves 0..2, 16 rows each)
    if (wv < 3){
      const _Float16* B3hb = wsu + 262144;
      const _Float16* B3lb = wsu + 266240;
      f32x4 a3 = 0.f;
      #pragma unroll 1
      for (int kk = 0; kk < 8; ++kk){
        int bi = (kk * 4 + hi) * 16 + ln;
        half8 Bhf = ((const half8*)B3hb)[bi];
        half8 Blf = ((const half8*)B3lb)[bi];
        int kx = lnb + ((kk * 64 + hi * 16) ^ swzx) + wv * 8192;  // row = wv*16+ln
        half8 Ah = *(const half8*)((const char*)hbuf_hi + kx);
        half8 Al = *(const half8*)((const char*)hbuf_lo + kx);
        a3 = __builtin_amdgcn_mfma_f32_16x16x32_f16(Ah, Bhf, a3, 0, 0, 0);
        a3 = __builtin_amdgcn_mfma_f32_16x16x32_f16(Ah, Blf, a3, 0, 0, 0);
        a3 = __builtin_amdgcn_mfma_f32_16x16x32_f16(Al, Bhf, a3, 0, 0, 0);
      }
      if (ln < 4){
        float b3v = b3[ln];
        #pragma unroll
        for (int r = 0; r < 4; ++r){
          int row = rbase + wv * 16 + hi * 4 + r;
          if (row < NSAMP) obuf[row * 4 + ln] = fmaf(a3[r], USC, b3v);
        }
      }
    }
    __syncthreads();   // L3 reads done before next chunk's layer-0 overwrites hbuf
  }

  // ---- epilogue: blend weights + outputs (threads 0..127 = waves 0,1)
  float inc = 1.f, alpha = 0.f, sig0 = 0.f, sig1 = 0.f, sig2 = 0.f;
  if (t < NSAMP){
    const float4* ov = (const float4*)obuf;
    float4 o = ov[t];
    sig0 = 1.f / (1.f + expf(-o.x));
    sig1 = 1.f / (1.f + expf(-o.y));
    sig2 = 1.f / (1.f + expf(-o.z));
    float op = (o.w > 20.f) ? o.w : log1pf(expf(o.w));
    float delta = (t < NSAMP - 1) ? (tl[t + 1] - tl[t]) : 1e10f;
    alpha = 1.f - expf(-op * delta);
    float u = fminf(1.f, 1.f - alpha + 1e-10f);
    inc = u;                               // inclusive product scan within wave
    #pragma unroll
    for (int off = 1; off < 64; off <<= 1){
      float v = __shfl_up(inc, off);
      if (lane >= off) inc *= v;
    }
    if (wv == 0 && lane == 63) stot = inc; // product of u[0..63]
  }
  __syncthreads();
  if (t < NSAMP){
    float ex = __shfl_up(inc, 1);
    if (lane == 0) ex = 1.f;
    if (wv == 1) ex *= stot;               // exclusive scan across waves
    float wgt = alpha * ex;
    float sr = wgt * sig0, sg = wgt * sig1, sb = wgt * sig2;
    float aw = (t < NSAMP - 1) ? wgt : 0.f;
    float wm = (t < NSAMP - 1) ? wgt : -1e30f;
    float wmv = wm;
    #pragma unroll
    for (int off = 32; off; off >>= 1){
      sr += __shfl_xor(sr, off);
      sg += __shfl_xor(sg, off);
      sb += __shfl_xor(sb, off);
      aw += __shfl_xor(aw, off);
      wm = fmaxf(wm, __shfl_xor(wm, off));
    }
    unsigned long long bal = __ballot(wmv == wm);
    int fi = __ffsll(bal) - 1;             // first max within wave
    if (lane == 0){
      redf[wv][0] = sr; redf[wv][1] = sg; redf[wv][2] = sb;
      redf[wv][3] = aw; redf[wv][4] = wm;
      redi[wv] = fi;
    }
  }
  __syncthreads();
  if (t == 0){
    float cr = redf[0][0] + redf[1][0];
    float cg = redf[0][1] + redf[1][1];
    float cb = redf[0][2] + redf[1][2];
    float asum = redf[0][3] + redf[1][3];
    int idx = (redf[1][4] > redf[0][4]) ? (64 + redi[1]) : redi[0]; // first max overall
    int cutoff = (asum < 0.1f) ? (NSAMP - 1) : idx;
    out[ray * 3 + 0] = cr;
    out[ray * 3 + 1] = cg;
    out[ray * 3 + 2] = cb;
    out[NRAYS * 3 + ray] = asum;
    out[NRAYS * 4 + ray] = tl[cutoff];
  }
}

extern "C" void kernel_launch(void* const* d_in, const int* in_sizes, int n_in,
                              void* d_out, int out_size, void* d_ws, size_t ws_size,
                              hipStream_t stream) {
  const float* pos = (const float*)d_in[0];
  const float* tv  = (const float*)d_in[1];
  const float* W0  = (const float*)d_in[2];
  const float* b0  = (const float*)d_in[3];
  const float* W1  = (const float*)d_in[4];
  const float* b1  = (const float*)d_in[5];
  const float* W2  = (const float*)d_in[6];
  const float* b2  = (const float*)d_in[7];
  const float* W3  = (const float*)d_in[8];
  const float* b3  = (const float*)d_in[9];
  _Float16* wsu = (_Float16*)d_ws;

  prep_kernel<<<528, 256, 0, stream>>>(W1, W2, W3, wsu);
  nerf_kernel<<<NRAYS, 256, 0, stream>>>(pos, tv, W0, b0, b1, b2, b3, wsu, (float*)d_out);
}

// Round 22
// 213.511 us; speedup vs baseline: 2.1814x; 1.0880x over previous
//
#include <hip/hip_runtime.h>

#define NRAYS 2048
#define NSAMP 128
#define HID   256
#define CROWS 32   // rows per chunk (4 chunks x 32 = 128, no padding)

typedef __attribute__((ext_vector_type(8))) _Float16 half8;
typedef __attribute__((ext_vector_type(4))) float f32x4;

__device__ __forceinline__ unsigned pack2(_Float16 a, _Float16 b){
  unsigned short ua = __builtin_bit_cast(unsigned short, a);
  unsigned short ub = __builtin_bit_cast(unsigned short, b);
  return (unsigned)ua | ((unsigned)ub << 16);
}

// ---- weight preprocess: fp32 row-major [K][N] -> fp16 hi/lo packed [K/8][N][8], scaled x256
// half offsets in ws: W1hi 0, W1lo 65536, W2hi 131072, W2lo 196608,
//                     W3hi 262144 (padded N=16, 4096), W3lo 266240
__global__ void prep_kernel(const float* __restrict__ W1,
                            const float* __restrict__ W2,
                            const float* __restrict__ W3,
                            _Float16* __restrict__ out)
{
  int idx = blockIdx.x * 256 + threadIdx.x;
  float v; int pk, base, lstep;
  if (idx < 65536){
    int k = idx >> 8, n = idx & 255;
    v = W1[idx] * 256.f; pk = (((k >> 3) << 8) + n) * 8 + (k & 7); base = 0; lstep = 65536;
  } else if (idx < 131072){
    int j = idx - 65536; int k = j >> 8, n = j & 255;
    v = W2[j] * 256.f; pk = (((k >> 3) << 8) + n) * 8 + (k & 7); base = 131072; lstep = 65536;
  } else if (idx < 135168){
    int j = idx - 131072;
    int n = (j >> 3) & 15;
    int k = ((j >> 7) << 3) | (j & 7);
    v = (n < 4) ? W3[k * 4 + n] * 256.f : 0.f; pk = j; base = 262144; lstep = 4096;
  } else return;
  _Float16 hi = (_Float16)v;
  _Float16 lo = (_Float16)(v - (float)hi);
  out[base + pk] = hi;
  out[base + lstep + pk] = lo;
}

// Four 32-row chunks per ray (no pad waste). Activation tile fp16 hi+lo = 32KB;
// block LDS ~36.9KB -> 4 blocks/CU by LDS even at 4KB granularity (r17 showed
// 53.76KB only fit 2 -> granularity/reserve coarser than 512B). 16 waves/CU.
// (256,2) = proven spill-free cap; acc 2x4 -> live ~90 regs.
__launch_bounds__(256, 2)
__global__ void nerf_kernel(const float* __restrict__ pos,
                            const float* __restrict__ tvals,
                            const float* __restrict__ W0,
                            const float* __restrict__ b0,
                            const float* __restrict__ b1,
                            const float* __restrict__ b2,
                            const float* __restrict__ b3,
                            const _Float16* __restrict__ wsu,
                            float* __restrict__ out)
{
  __shared__ __align__(16) _Float16 hbuf_hi[CROWS * HID]; // 16 KB swizzled
  __shared__ __align__(16) _Float16 hbuf_lo[CROWS * HID]; // 16 KB swizzled
  __shared__ float xls[NSAMP * 3];
  __shared__ float tl[NSAMP];
  __shared__ __align__(16) float obuf[NSAMP * 4];
  __shared__ float stot;
  __shared__ float redf[2][5];
  __shared__ int   redi[2];

  const int t    = threadIdx.x;
  const int ray  = blockIdx.x;
  const int lane = t & 63;
  const int wv   = t >> 6;     // wave id 0..3
  const int ln   = lane & 15;
  const int hi   = lane >> 4;
  const int swzx = (ln & 7) << 4;
  const float USC = 1.f / 65536.f;

  // ---- stage inputs
  {
    const float* pbase = pos + (size_t)ray * NSAMP * 3;
    xls[t] = pbase[t];
    if (t < NSAMP) xls[256 + t] = pbase[256 + t];
    if (t < NSAMP) tl[t] = tvals[(size_t)ray * NSAMP + t];
  }
  __syncthreads();

  const int c = (t & 127) << 1;   // two adjacent cols per thread (layer 0)
  const int lnb = ln * 512;       // row byte base (row = mb*16+ln -> +mb*8192)

  for (int chunk = 0; chunk < 4; ++chunk){
    const int rbase = chunk * CROWS;

    // ---- layer 0: x(32x3) @ W0(3x256) + b0, relu -> hbuf hi/lo (x256, swizzled)
    {
      float wa0 = W0[c],       wb0 = W0[c + 1];
      float wa1 = W0[256 + c], wb1 = W0[256 + c + 1];
      float wa2 = W0[512 + c], wb2 = W0[512 + c + 1];
      float ba = b0[c], bb = b0[c + 1];
      int r0 = (t >> 7) << 4;    // rows 0..15 or 16..31 (local)
      for (int r = r0; r < r0 + 16; ++r){
        int gr = rbase + r;
        float x0 = xls[gr * 3 + 0], x1 = xls[gr * 3 + 1], x2 = xls[gr * 3 + 2];
        float ha = fmaxf(fmaf(x2, wa2, fmaf(x1, wa1, fmaf(x0, wa0, ba))), 0.f) * 256.f;
        float hb = fmaxf(fmaf(x2, wb2, fmaf(x1, wb1, fmaf(x0, wb0, bb))), 0.f) * 256.f;
        _Float16 ah = (_Float16)ha, bh = (_Float16)hb;
        _Float16 al = (_Float16)(ha - (float)ah), bl = (_Float16)(hb - (float)bh);
        int off = (r * 512 + c * 2) ^ ((r & 7) << 4);
        *(unsigned*)((char*)hbuf_hi + off) = pack2(ah, bh);
        *(unsigned*)((char*)hbuf_lo + off) = pack2(al, bl);
      }
    }
    __syncthreads();

    // ---- layers 1,2: h(32x256) @ W(256x256) + b, relu. fp16 split MFMA (3 per product)
    for (int L = 0; L < 2; ++L){
      const _Float16* Bhb = wsu + (L ? 131072 : 0);
      const _Float16* Blb = wsu + (L ? 196608 : 65536);
      const float* bias = L ? b2 : b1;
      const int n0 = wv * 64;

      f32x4 acc[2][4];
      #pragma unroll
      for (int mb = 0; mb < 2; ++mb)
        #pragma unroll
        for (int nb = 0; nb < 4; ++nb)
          acc[mb][nb] = 0.f;

      #pragma unroll 1            // RUNTIME loop: prevents B-load hoisting across kk
      for (int kk = 0; kk < 8; ++kk){
        const half8* Bhp = (const half8*)Bhb + (kk * 4 + hi) * 256 + n0 + ln;
        const half8* Blp = (const half8*)Blb + (kk * 4 + hi) * 256 + n0 + ln;
        half8 Bhf[4], Blf[4];
        #pragma unroll
        for (int nb = 0; nb < 4; ++nb){
          Bhf[nb] = Bhp[nb * 16];
          Blf[nb] = Blp[nb * 16];
        }
        int kx = lnb + ((kk * 64 + hi * 16) ^ swzx);
        #pragma unroll
        for (int mb = 0; mb < 2; ++mb){
          half8 Ahf = *(const half8*)((const char*)hbuf_hi + kx + mb * 8192);
          half8 Alf = *(const half8*)((const char*)hbuf_lo + kx + mb * 8192);
          #pragma unroll
          for (int nb = 0; nb < 4; ++nb)
            acc[mb][nb] = __builtin_amdgcn_mfma_f32_16x16x32_f16(Ahf, Bhf[nb], acc[mb][nb], 0, 0, 0);
          #pragma unroll
          for (int nb = 0; nb < 4; ++nb)
            acc[mb][nb] = __builtin_amdgcn_mfma_f32_16x16x32_f16(Ahf, Blf[nb], acc[mb][nb], 0, 0, 0);
          #pragma unroll
          for (int nb = 0; nb < 4; ++nb)
            acc[mb][nb] = __builtin_amdgcn_mfma_f32_16x16x32_f16(Alf, Bhf[nb], acc[mb][nb], 0, 0, 0);
        }
      }

      float bv[4];
      #pragma unroll
      for (int nb = 0; nb < 4; ++nb) bv[nb] = bias[n0 + nb * 16 + ln];

      __syncthreads();   // all waves done reading hbuf before in-place overwrite
      #pragma unroll
      for (int mb = 0; mb < 2; ++mb){
        #pragma unroll
        for (int nb = 0; nb < 4; ++nb){
          int col = n0 + nb * 16 + ln;
          #pragma unroll
          for (int r = 0; r < 4; ++r){
            int row = mb * 16 + hi * 4 + r;
            float f = fmaxf(fmaf(acc[mb][nb][r], USC, bv[nb]), 0.f) * 256.f;
            _Float16 fh = (_Float16)f;
            _Float16 fl = (_Float16)(f - (float)fh);
            int off = (row * 512 + col * 2) ^ ((row & 7) << 4);
            *(_Float16*)((char*)hbuf_hi + off) = fh;
            *(_Float16*)((char*)hbuf_lo + off) = fl;
          }
        }
      }
      __syncthreads();
    }

    // ---- layer 3: h(32x256) @ W3(256x4) + b3 -> obuf f32 (waves 0,1: 16 rows each)
    if (wv < 2){
      const _Float16* B3hb = wsu + 262144;
      const _Float16* B3lb = wsu + 266240;
      f32x4 a3 = 0.f;
      #pragma unroll 1
      for (int kk = 0; kk < 8; ++kk){
        int bi = (kk * 4 + hi) * 16 + ln;
        half8 Bhf = ((const half8*)B3hb)[bi];
        half8 Blf = ((const half8*)B3lb)[bi];
        int kx = lnb + ((kk * 64 + hi * 16) ^ swzx) + wv * 8192;  // row = wv*16+ln
        half8 Ah = *(const half8*)((const char*)hbuf_hi + kx);
        half8 Al = *(const half8*)((const char*)hbuf_lo + kx);
        a3 = __builtin_amdgcn_mfma_f32_16x16x32_f16(Ah, Bhf, a3, 0, 0, 0);
        a3 = __builtin_amdgcn_mfma_f32_16x16x32_f16(Ah, Blf, a3, 0, 0, 0);
        a3 = __builtin_amdgcn_mfma_f32_16x16x32_f16(Al, Bhf, a3, 0, 0, 0);
      }
      if (ln < 4){
        float b3v = b3[ln];
        #pragma unroll
        for (int r = 0; r < 4; ++r){
          int row = rbase + wv * 16 + hi * 4 + r;
          obuf[row * 4 + ln] = fmaf(a3[r], USC, b3v);
        }
      }
    }
    __syncthreads();   // L3 reads done before next chunk's layer-0 overwrites hbuf
  }

  // ---- epilogue: blend weights + outputs (threads 0..127 = waves 0,1)
  float inc = 1.f, alpha = 0.f, sig0 = 0.f, sig1 = 0.f, sig2 = 0.f;
  if (t < NSAMP){
    const float4* ov = (const float4*)obuf;
    float4 o = ov[t];
    sig0 = 1.f / (1.f + expf(-o.x));
    sig1 = 1.f / (1.f + expf(-o.y));
    sig2 = 1.f / (1.f + expf(-o.z));
    float op = (o.w > 20.f) ? o.w : log1pf(expf(o.w));
    float delta = (t < NSAMP - 1) ? (tl[t + 1] - tl[t]) : 1e10f;
    alpha = 1.f - expf(-op * delta);
    float u = fminf(1.f, 1.f - alpha + 1e-10f);
    inc = u;                               // inclusive product scan within wave
    #pragma unroll
    for (int off = 1; off < 64; off <<= 1){
      float v = __shfl_up(inc, off);
      if (lane >= off) inc *= v;
    }
    if (wv == 0 && lane == 63) stot = inc; // product of u[0..63]
  }
  __syncthreads();
  if (t < NSAMP){
    float ex = __shfl_up(inc, 1);
    if (lane == 0) ex = 1.f;
    if (wv == 1) ex *= stot;               // exclusive scan across waves
    float wgt = alpha * ex;
    float sr = wgt * sig0, sg = wgt * sig1, sb = wgt * sig2;
    float aw = (t < NSAMP - 1) ? wgt : 0.f;
    float wm = (t < NSAMP - 1) ? wgt : -1e30f;
    float wmv = wm;
    #pragma unroll
    for (int off = 32; off; off >>= 1){
      sr += __shfl_xor(sr, off);
      sg += __shfl_xor(sg, off);
      sb += __shfl_xor(sb, off);
      aw += __shfl_xor(aw, off);
      wm = fmaxf(wm, __shfl_xor(wm, off));
    }
    unsigned long long bal = __ballot(wmv == wm);
    int fi = __ffsll(bal) - 1;             // first max within wave
    if (lane == 0){
      redf[wv][0] = sr; redf[wv][1] = sg; redf[wv][2] = sb;
      redf[wv][3] = aw; redf[wv][4] = wm;
      redi[wv] = fi;
    }
  }
  __syncthreads();
  if (t == 0){
    float cr = redf[0][0] + redf[1][0];
    float cg = redf[0][1] + redf[1][1];
    float cb = redf[0][2] + redf[1][2];
    float asum = redf[0][3] + redf[1][3];
    int idx = (redf[1][4] > redf[0][4]) ? (64 + redi[1]) : redi[0]; // first max overall
    int cutoff = (asum < 0.1f) ? (NSAMP - 1) : idx;
    out[ray * 3 + 0] = cr;
    out[ray * 3 + 1] = cg;
    out[ray * 3 + 2] = cb;
    out[NRAYS * 3 + ray] = asum;
    out[NRAYS * 4 + ray] = tl[cutoff];
  }
}

extern "C" void kernel_launch(void* const* d_in, const int* in_sizes, int n_in,
                              void* d_out, int out_size, void* d_ws, size_t ws_size,
                              hipStream_t stream) {
  const float* pos = (const float*)d_in[0];
  const float* tv  = (const float*)d_in[1];
  const float* W0  = (const float*)d_in[2];
  const float* b0  = (const float*)d_in[3];
  const float* W1  = (const float*)d_in[4];
  const float* b1  = (const float*)d_in[5];
  const float* W2  = (const float*)d_in[6];
  const float* b2  = (const float*)d_in[7];
  const float* W3  = (const float*)d_in[8];
  const float* b3  = (const float*)d_in[9];
  _Float16* wsu = (_Float16*)d_ws;

  prep_kernel<<<528, 256, 0, stream>>>(W1, W2, W3, wsu);
  nerf_kernel<<<NRAYS, 256, 0, stream>>>(pos, tv, W0, b0, b1, b2, b3, wsu, (float*)d_out);
}